// Round 9
// baseline (135.100 us; speedup 1.0000x reference)
//
#include <hip/hip_runtime.h>
#include <math.h>

#define NB    512
#define NP    4096
#define BLOCK 256
#define KPT   2
#define CHUNK (BLOCK * KPT)     // 512 points per block
#define NCHUNK (NP / CHUNK)     // 8 chunks per batch element

typedef float v2f __attribute__((ext_vector_type(2)));

// ---- explicit VOP3P packed-f32 ops (per-lane IEEE f32; bit-exact) ----
__device__ __forceinline__ v2f pk_mul(v2f a, v2f b) {
    v2f d;
    asm("v_pk_mul_f32 %0, %1, %2" : "=v"(d) : "v"(a), "v"(b));
    return d;
}
__device__ __forceinline__ v2f pk_add(v2f a, v2f b) {
    v2f d;
    asm("v_pk_add_f32 %0, %1, %2" : "=v"(d) : "v"(a), "v"(b));
    return d;
}
__device__ __forceinline__ v2f pk_fma(v2f a, v2f b, v2f c) {
    v2f d;
    asm("v_pk_fma_f32 %0, %1, %2, %3" : "=v"(d) : "v"(a), "v"(b), "v"(c));
    return d;
}
#define PK2(c) ((v2f){(c), (c)})

// fp32 sin, correctly rounded (fp64 Taylor after exact revolution reduction).
// Bit-identical to R4..R8. ONLY for layer 1 (output amplification ~4e5x).
__device__ __forceinline__ float sin_cr(float tf) {
#pragma clang fp contract(off)
    double t  = (double)tf;
    double y  = t * 0.15915494309189535;    // t/(2pi)
    double f  = y - rint(y);                // [-0.5,0.5], exact subtraction
    double x  = f * 6.283185307179586;      // [-pi,pi]
    double x2 = x * x;
    double p;
    p =                  1.0 / 51090942171709440000.0;   // +1/21!
    p = fma(p, x2, -1.0 / 121645100408832000.0);         // -1/19!
    p = fma(p, x2,  1.0 / 355687428096000.0);            // +1/17!
    p = fma(p, x2, -1.0 / 1307674368000.0);              // -1/15!
    p = fma(p, x2,  1.0 / 6227020800.0);                 // +1/13!
    p = fma(p, x2, -1.0 / 39916800.0);                   // -1/11!
    p = fma(p, x2,  1.0 / 362880.0);                     // +1/9!
    p = fma(p, x2, -1.0 / 5040.0);                       // -1/7!
    p = fma(p, x2,  1.0 / 120.0);                        // +1/5!
    p = fma(p, x2, -1.0 / 6.0);                          // -1/3!
    double x3 = x2 * x;
    return (float)fma(p, x3, x);
}

// Fast all-f32 packed sin for layers 2/3. Same arithmetic as R8's sin2_fast
// (Cody-Waite 2-part 2pi reduction + Taylor-19), now with explicit pk ops.
// Per-lane fp32 fma semantics -> values equivalent to R8 (err ~5e-7 vs true).
__device__ __forceinline__ v2f sin2_fast(v2f t) {
    v2f y = pk_mul(t, PK2(0.15915494309189535f));
    v2f n;
    n.x = rintf(y.x);
    n.y = rintf(y.y);
    v2f r = pk_fma(n, PK2(-6.28125f), t);          // exact CW hi part
    r = pk_fma(n, PK2(-1.93530717e-3f), r);        // CW lo part
    v2f r2 = pk_mul(r, r);
    v2f p = PK2(-8.22063525e-18f);                 // -1/19!
    p = pk_fma(p, r2, PK2( 2.81145725e-15f));      // +1/17!
    p = pk_fma(p, r2, PK2(-7.64716373e-13f));      // -1/15!
    p = pk_fma(p, r2, PK2( 1.60590438e-10f));      // +1/13!
    p = pk_fma(p, r2, PK2(-2.50521084e-8f));       // -1/11!
    p = pk_fma(p, r2, PK2( 2.75573192e-6f));       // +1/9!
    p = pk_fma(p, r2, PK2(-1.98412698e-4f));       // -1/7!
    p = pk_fma(p, r2, PK2( 8.33333333e-3f));       // +1/5!
    p = pk_fma(p, r2, PK2(-1.66666667e-1f));       // -1/3!
    v2f r3 = pk_mul(r2, r);
    return pk_fma(p, r3, r);
}

// numpy n=20 dot (SSE2 npyv, no FMA): 4 columns, chained mul+add per column,
// tree (c0+c2)+(c1+c3). Explicit pk ops; wd holds duplicated weights.
__device__ __forceinline__ v2f dot20_pk(const v2f* __restrict__ wd,
                                        const v2f* __restrict__ h) {
    v2f c0 = pk_mul(h[0], wd[0]);
    v2f c1 = pk_mul(h[1], wd[1]);
    v2f c2 = pk_mul(h[2], wd[2]);
    v2f c3 = pk_mul(h[3], wd[3]);
    c0 = pk_add(c0, pk_mul(h[4],  wd[4]));
    c1 = pk_add(c1, pk_mul(h[5],  wd[5]));
    c2 = pk_add(c2, pk_mul(h[6],  wd[6]));
    c3 = pk_add(c3, pk_mul(h[7],  wd[7]));
    c0 = pk_add(c0, pk_mul(h[8],  wd[8]));
    c1 = pk_add(c1, pk_mul(h[9],  wd[9]));
    c2 = pk_add(c2, pk_mul(h[10], wd[10]));
    c3 = pk_add(c3, pk_mul(h[11], wd[11]));
    c0 = pk_add(c0, pk_mul(h[12], wd[12]));
    c1 = pk_add(c1, pk_mul(h[13], wd[13]));
    c2 = pk_add(c2, pk_mul(h[14], wd[14]));
    c3 = pk_add(c3, pk_mul(h[15], wd[15]));
    c0 = pk_add(c0, pk_mul(h[16], wd[16]));
    c1 = pk_add(c1, pk_mul(h[17], wd[17]));
    c2 = pk_add(c2, pk_mul(h[18], wd[18]));
    c3 = pk_add(c3, pk_mul(h[19], wd[19]));
    v2f s02 = pk_add(c0, c2);
    v2f s13 = pk_add(c1, c3);
    return pk_add(s02, s13);
}

// Param layout per batch (921 floats):
// [0,40) W1(20x2)  [40,60) b1 | [60,460) W2(20x20) [460,480) b2
// [480,880) W3(20x20) [880,900) b3 | [900,920) W4(1x20) [920] b4
// LDS holds weights duplicated into both halves of a float2 so they feed
// VOP3P pk ops directly (no op_sel broadcast needed).
__global__ __launch_bounds__(BLOCK) void siren20_pk_kernel(
    const float* __restrict__ coords,
    const float* __restrict__ wflat,
    float* __restrict__ out)
{
#pragma clang fp contract(off)
    __shared__ __align__(16) v2f wd[928];
    const int b   = blockIdx.y;
    const int tid = threadIdx.x;
    const float* __restrict__ wg = wflat + (size_t)b * 921;

    #pragma unroll
    for (int k = 0; k < 4; ++k) {
        int i = tid + k * BLOCK;
        if (i < 921) {
            float v = wg[i];
            v2f d; d.x = v; d.y = v;
            wd[i] = d;
        }
    }
    __syncthreads();

    const int p0 = blockIdx.x * CHUNK + tid;   // two coalesced points
    const int p1 = p0 + BLOCK;
    const float2* cbase = (const float2*)(coords + (size_t)b * NP * 2);
    const float2 ca = cbase[p0];
    const float2 cc = cbase[p1];
    v2f cx; cx.x = ca.x; cx.y = cc.x;
    v2f cy; cy.x = ca.y; cy.y = cc.y;

    v2f h[20], g[20];

    // Layer 1: n=2 scalar dot (mul, add; no fma), +b, *20, CR sin per lane.
    #pragma unroll
    for (int j = 0; j < 20; ++j) {
        v2f s = pk_mul(cx, wd[2 * j]);
        s = pk_add(s, pk_mul(cy, wd[2 * j + 1]));
        v2f u = pk_add(s, wd[40 + j]);
        v2f t = pk_mul(u, PK2(20.0f));
        h[j].x = sin_cr(t.x);
        h[j].y = sin_cr(t.y);
    }

    // Layer 2: W at 60, b at 460 — fast packed sin
    #pragma unroll
    for (int j = 0; j < 20; ++j) {
        v2f a = dot20_pk(&wd[60 + 20 * j], h);
        v2f u = pk_add(a, wd[460 + j]);
        v2f t = pk_mul(u, PK2(20.0f));
        g[j] = sin2_fast(t);
    }

    // Layer 3: W at 480, b at 880 — fast packed sin
    #pragma unroll
    for (int j = 0; j < 20; ++j) {
        v2f a = dot20_pk(&wd[480 + 20 * j], g);
        v2f u = pk_add(a, wd[880 + j]);
        v2f t = pk_mul(u, PK2(20.0f));
        h[j] = sin2_fast(t);
    }

    // Layer 4: W at 900, b at 920, clip
    v2f a = dot20_pk(&wd[900], h);
    v2f u = pk_add(a, wd[920]);
    float r0 = fminf(fmaxf(u.x, 0.0f), 1.0f);
    float r1 = fminf(fmaxf(u.y, 0.0f), 1.0f);

    float* ob = out + (size_t)b * NP;
    ob[p0] = r0;
    ob[p1] = r1;
}

extern "C" void kernel_launch(void* const* d_in, const int* in_sizes, int n_in,
                              void* d_out, int out_size, void* d_ws, size_t ws_size,
                              hipStream_t stream) {
    const float* coords = (const float*)d_in[0];
    const float* wflat  = (const float*)d_in[1];
    float* out = (float*)d_out;
    dim3 grid(NCHUNK, NB);
    siren20_pk_kernel<<<grid, dim3(BLOCK), 0, stream>>>(coords, wflat, out);
}

// Round 10
// 92.571 us; speedup vs baseline: 1.4594x; 1.4594x over previous
//
#include <hip/hip_runtime.h>
#include <math.h>

#define NB    512
#define NP    4096
#define BLOCK 256
#define KPT   2
#define CHUNK (BLOCK * KPT)     // 512 points per block
#define NCHUNK (NP / CHUNK)     // 8 chunks per batch element

typedef float v2f __attribute__((ext_vector_type(2)));

// fp32 sin, correctly rounded (fp64 Taylor after exact revolution reduction).
// Bit-identical to R4..R9. ONLY for layer 1 (output amplification ~2e4x).
__device__ __forceinline__ float sin_cr(float tf) {
#pragma clang fp contract(off)
    double t  = (double)tf;
    double y  = t * 0.15915494309189535;    // t/(2pi)
    double f  = y - rint(y);                // [-0.5,0.5], exact subtraction
    double x  = f * 6.283185307179586;      // [-pi,pi]
    double x2 = x * x;
    double p;
    p =                  1.0 / 51090942171709440000.0;   // +1/21!
    p = fma(p, x2, -1.0 / 121645100408832000.0);         // -1/19!
    p = fma(p, x2,  1.0 / 355687428096000.0);            // +1/17!
    p = fma(p, x2, -1.0 / 1307674368000.0);              // -1/15!
    p = fma(p, x2,  1.0 / 6227020800.0);                 // +1/13!
    p = fma(p, x2, -1.0 / 39916800.0);                   // -1/11!
    p = fma(p, x2,  1.0 / 362880.0);                     // +1/9!
    p = fma(p, x2, -1.0 / 5040.0);                       // -1/7!
    p = fma(p, x2,  1.0 / 120.0);                        // +1/5!
    p = fma(p, x2, -1.0 / 6.0);                          // -1/3!
    double x3 = x2 * x;
    return (float)fma(p, x3, x);
}

// L2/L3 sin: Cody-Waite reduce to [-pi,pi] (err ~1e-7), scale to revolutions,
// hardware v_sin_f32 (err ~1-2 ulp). Total err ~1e-6 vs true sin — R8 proved
// 5e-7 invisible at output; budget says 1e-6 x 280 amplification ~ 3e-4.
__device__ __forceinline__ v2f sin2_hw(v2f t) {
#pragma clang fp contract(fast)
    v2f y = t * 0.15915494309189535f;
    v2f n;
    n.x = rintf(y.x);
    n.y = rintf(y.y);
    v2f r = t - n * 6.28125f;            // exact CW hi part (fused fma)
    r = r - n * 1.93530717e-3f;          // CW lo part (fused fma)
    v2f s = r * 0.15915494309189535f;    // revolutions, [-0.5,0.5]
    v2f o;
    o.x = __builtin_amdgcn_sinf(s.x);
    o.y = __builtin_amdgcn_sinf(s.y);
    return o;
}

// numpy n=20 dot (SSE2 npyv, no FMA): 4 columns, chained mul+add per column,
// tree (c0+c2)+(c1+c3). Exact numpy rounding — used for layer 2.
__device__ __forceinline__ v2f dot20_np2(const float* __restrict__ wr,
                                         const v2f* __restrict__ h) {
#pragma clang fp contract(off)
    v2f c0 = h[0] * wr[0];
    v2f c1 = h[1] * wr[1];
    v2f c2 = h[2] * wr[2];
    v2f c3 = h[3] * wr[3];
    c0 = c0 + h[4]  * wr[4];   c1 = c1 + h[5]  * wr[5];
    c2 = c2 + h[6]  * wr[6];   c3 = c3 + h[7]  * wr[7];
    c0 = c0 + h[8]  * wr[8];   c1 = c1 + h[9]  * wr[9];
    c2 = c2 + h[10] * wr[10];  c3 = c3 + h[11] * wr[11];
    c0 = c0 + h[12] * wr[12];  c1 = c1 + h[13] * wr[13];
    c2 = c2 + h[14] * wr[14];  c3 = c3 + h[15] * wr[15];
    c0 = c0 + h[16] * wr[16];  c1 = c1 + h[17] * wr[17];
    c2 = c2 + h[18] * wr[18];  c3 = c3 + h[19] * wr[19];
    v2f s02 = c0 + c2;
    v2f s13 = c1 + c3;
    return s02 + s13;
}

// Same column structure but contraction allowed -> mul+add fuse into pk_fma.
// Reorder error ~ulp-level; used for layers 3/4 where output amplification
// is ~4.5x (safe).
__device__ __forceinline__ v2f dot20_fma(const float* __restrict__ wr,
                                         const v2f* __restrict__ h) {
#pragma clang fp contract(fast)
    v2f c0 = h[0] * wr[0];
    v2f c1 = h[1] * wr[1];
    v2f c2 = h[2] * wr[2];
    v2f c3 = h[3] * wr[3];
    c0 = c0 + h[4]  * wr[4];   c1 = c1 + h[5]  * wr[5];
    c2 = c2 + h[6]  * wr[6];   c3 = c3 + h[7]  * wr[7];
    c0 = c0 + h[8]  * wr[8];   c1 = c1 + h[9]  * wr[9];
    c2 = c2 + h[10] * wr[10];  c3 = c3 + h[11] * wr[11];
    c0 = c0 + h[12] * wr[12];  c1 = c1 + h[13] * wr[13];
    c2 = c2 + h[14] * wr[14];  c3 = c3 + h[15] * wr[15];
    c0 = c0 + h[16] * wr[16];  c1 = c1 + h[17] * wr[17];
    c2 = c2 + h[18] * wr[18];  c3 = c3 + h[19] * wr[19];
    v2f s02 = c0 + c2;
    v2f s13 = c1 + c3;
    return s02 + s13;
}

// Param layout per batch (921 floats):
// [0,40) W1(20x2)  [40,60) b1 | [60,460) W2(20x20) [460,480) b2
// [480,880) W3(20x20) [880,900) b3 | [900,920) W4(1x20) [920] b4
__global__ __launch_bounds__(BLOCK) void siren20_np6_kernel(
    const float* __restrict__ coords,
    const float* __restrict__ wflat,
    float* __restrict__ out)
{
#pragma clang fp contract(off)
    __shared__ __align__(16) float w[928];
    const int b   = blockIdx.y;
    const int tid = threadIdx.x;
    const float* __restrict__ wg = wflat + (size_t)b * 921;

    #pragma unroll
    for (int k = 0; k < 4; ++k) {
        int i = tid + k * BLOCK;
        if (i < 921) w[i] = wg[i];
    }
    __syncthreads();

    const int p0 = blockIdx.x * CHUNK + tid;   // two coalesced points
    const int p1 = p0 + BLOCK;
    const float2* cbase = (const float2*)(coords + (size_t)b * NP * 2);
    const float2 ca = cbase[p0];
    const float2 cc = cbase[p1];
    v2f cx; cx.x = ca.x; cx.y = cc.x;
    v2f cy; cy.x = ca.y; cy.y = cc.y;

    v2f h[20], g[20];

    // Layer 1: n=2 scalar dot (mul, add; no fma), +b, *20, CR sin per lane.
    #pragma unroll
    for (int j = 0; j < 20; ++j) {
        v2f s = cx * w[2 * j];
        s = s + cy * w[2 * j + 1];
        v2f u = s + w[40 + j];
        v2f t = u * 20.0f;
        h[j].x = sin_cr(t.x);
        h[j].y = sin_cr(t.y);
    }

    // Layer 2: W at 60, b at 460 — exact numpy dot, hw sin
    #pragma unroll
    for (int j = 0; j < 20; ++j) {
        v2f a = dot20_np2(&w[60 + 20 * j], h);
        v2f u = a + w[460 + j];
        v2f t = u * 20.0f;
        g[j] = sin2_hw(t);
    }

    // Layer 3: W at 480, b at 880 — fma dot, hw sin
    #pragma unroll
    for (int j = 0; j < 20; ++j) {
        v2f a = dot20_fma(&w[480 + 20 * j], g);
        v2f u = a + w[880 + j];
        v2f t = u * 20.0f;
        h[j] = sin2_hw(t);
    }

    // Layer 4: W at 900, b at 920, clip — fma dot
    v2f a = dot20_fma(&w[900], h);
    v2f u = a + w[920];
    float r0 = fminf(fmaxf(u.x, 0.0f), 1.0f);
    float r1 = fminf(fmaxf(u.y, 0.0f), 1.0f);

    float* ob = out + (size_t)b * NP;
    ob[p0] = r0;
    ob[p1] = r1;
}

extern "C" void kernel_launch(void* const* d_in, const int* in_sizes, int n_in,
                              void* d_out, int out_size, void* d_ws, size_t ws_size,
                              hipStream_t stream) {
    const float* coords = (const float*)d_in[0];
    const float* wflat  = (const float*)d_in[1];
    float* out = (float*)d_out;
    dim3 grid(NCHUNK, NB);
    siren20_np6_kernel<<<grid, dim3(BLOCK), 0, stream>>>(coords, wflat, out);
}

// Round 11
// 92.476 us; speedup vs baseline: 1.4609x; 1.0010x over previous
//
#include <hip/hip_runtime.h>
#include <math.h>

#define NB    512
#define NP    4096
#define BLOCK 256
#define KPT   2
#define CHUNK (BLOCK * KPT)     // 512 points per block
#define NCHUNK (NP / CHUNK)     // 8 chunks per batch element

typedef float v2f __attribute__((ext_vector_type(2)));

// ---- VOP3P packed f32 with op_sel broadcast of one 32-bit half ----
// wpair holds two CONSECUTIVE scalar weights (w[2k], w[2k+1]).
// _bl: both result halves use wpair.lo ; _bh: both use wpair.hi.
// Per-lane semantics = plain IEEE f32 mul/fma -> bit-identical per point.
__device__ __forceinline__ v2f pk_mul_bl(v2f a, v2f w) {
    v2f d;
    asm("v_pk_mul_f32 %0, %1, %2 op_sel:[0,0] op_sel_hi:[1,0]"
        : "=v"(d) : "v"(a), "v"(w));
    return d;
}
__device__ __forceinline__ v2f pk_mul_bh(v2f a, v2f w) {
    v2f d;
    asm("v_pk_mul_f32 %0, %1, %2 op_sel:[0,1] op_sel_hi:[1,1]"
        : "=v"(d) : "v"(a), "v"(w));
    return d;
}
__device__ __forceinline__ v2f pk_fma_bl(v2f a, v2f w, v2f c) {
    v2f d;
    asm("v_pk_fma_f32 %0, %1, %2, %3 op_sel:[0,0,0] op_sel_hi:[1,0,1]"
        : "=v"(d) : "v"(a), "v"(w), "v"(c));
    return d;
}
__device__ __forceinline__ v2f pk_fma_bh(v2f a, v2f w, v2f c) {
    v2f d;
    asm("v_pk_fma_f32 %0, %1, %2, %3 op_sel:[0,1,0] op_sel_hi:[1,1,1]"
        : "=v"(d) : "v"(a), "v"(w), "v"(c));
    return d;
}
__device__ __forceinline__ v2f pk_add(v2f a, v2f b) {
    v2f d;
    asm("v_pk_add_f32 %0, %1, %2 op_sel:[0,0] op_sel_hi:[1,1]"
        : "=v"(d) : "v"(a), "v"(b));
    return d;
}

// fp32 sin, correctly rounded (fp64 Taylor after exact revolution reduction).
// Bit-identical to R4..R10. ONLY for layer 1.
__device__ __forceinline__ float sin_cr(float tf) {
#pragma clang fp contract(off)
    double t  = (double)tf;
    double y  = t * 0.15915494309189535;    // t/(2pi)
    double f  = y - rint(y);                // [-0.5,0.5], exact subtraction
    double x  = f * 6.283185307179586;      // [-pi,pi]
    double x2 = x * x;
    double p;
    p =                  1.0 / 51090942171709440000.0;   // +1/21!
    p = fma(p, x2, -1.0 / 121645100408832000.0);         // -1/19!
    p = fma(p, x2,  1.0 / 355687428096000.0);            // +1/17!
    p = fma(p, x2, -1.0 / 1307674368000.0);              // -1/15!
    p = fma(p, x2,  1.0 / 6227020800.0);                 // +1/13!
    p = fma(p, x2, -1.0 / 39916800.0);                   // -1/11!
    p = fma(p, x2,  1.0 / 362880.0);                     // +1/9!
    p = fma(p, x2, -1.0 / 5040.0);                       // -1/7!
    p = fma(p, x2,  1.0 / 120.0);                        // +1/5!
    p = fma(p, x2, -1.0 / 6.0);                          // -1/3!
    double x3 = x2 * x;
    return (float)fma(p, x3, x);
}

// L2/L3 sin: Cody-Waite reduce, scale to revolutions, hardware v_sin_f32.
// Identical to R10 (proven: error invisible at output).
__device__ __forceinline__ v2f sin2_hw(v2f t) {
#pragma clang fp contract(fast)
    v2f y = t * 0.15915494309189535f;
    v2f n;
    n.x = rintf(y.x);
    n.y = rintf(y.y);
    v2f r = t - n * 6.28125f;            // exact CW hi part (fused fma)
    r = r - n * 1.93530717e-3f;          // CW lo part (fused fma)
    v2f s = r * 0.15915494309189535f;    // revolutions, [-0.5,0.5]
    v2f o;
    o.x = __builtin_amdgcn_sinf(s.x);
    o.y = __builtin_amdgcn_sinf(s.y);
    return o;
}

// numpy n=20 dot, EXACT order (separate mul/add), packed via op_sel:
// column l = i mod 4: c_l = (((w_l*h_l + w_{l+4}h_{l+4}) + ...)),
// tree (c0+c2)+(c1+c3). wp[k] = {w[2k], w[2k+1]} straight from scalar LDS.
__device__ __forceinline__ v2f dot20_pk_np(const v2f* __restrict__ wp,
                                           const v2f* __restrict__ h) {
    v2f c0 = pk_mul_bl(h[0],  wp[0]);
    v2f c1 = pk_mul_bh(h[1],  wp[0]);
    v2f c2 = pk_mul_bl(h[2],  wp[1]);
    v2f c3 = pk_mul_bh(h[3],  wp[1]);
    c0 = pk_add(c0, pk_mul_bl(h[4],  wp[2]));
    c1 = pk_add(c1, pk_mul_bh(h[5],  wp[2]));
    c2 = pk_add(c2, pk_mul_bl(h[6],  wp[3]));
    c3 = pk_add(c3, pk_mul_bh(h[7],  wp[3]));
    c0 = pk_add(c0, pk_mul_bl(h[8],  wp[4]));
    c1 = pk_add(c1, pk_mul_bh(h[9],  wp[4]));
    c2 = pk_add(c2, pk_mul_bl(h[10], wp[5]));
    c3 = pk_add(c3, pk_mul_bh(h[11], wp[5]));
    c0 = pk_add(c0, pk_mul_bl(h[12], wp[6]));
    c1 = pk_add(c1, pk_mul_bh(h[13], wp[6]));
    c2 = pk_add(c2, pk_mul_bl(h[14], wp[7]));
    c3 = pk_add(c3, pk_mul_bh(h[15], wp[7]));
    c0 = pk_add(c0, pk_mul_bl(h[16], wp[8]));
    c1 = pk_add(c1, pk_mul_bh(h[17], wp[8]));
    c2 = pk_add(c2, pk_mul_bl(h[18], wp[9]));
    c3 = pk_add(c3, pk_mul_bh(h[19], wp[9]));
    v2f s02 = pk_add(c0, c2);
    v2f s13 = pk_add(c1, c3);
    return pk_add(s02, s13);
}

// Same columns, fma-contracted (layers 3/4 — same per-lane fma rounding as
// R10's contracted dots; amplification there ~4.5x, safe).
__device__ __forceinline__ v2f dot20_pk_fma(const v2f* __restrict__ wp,
                                            const v2f* __restrict__ h) {
    v2f c0 = pk_mul_bl(h[0],  wp[0]);
    v2f c1 = pk_mul_bh(h[1],  wp[0]);
    v2f c2 = pk_mul_bl(h[2],  wp[1]);
    v2f c3 = pk_mul_bh(h[3],  wp[1]);
    c0 = pk_fma_bl(h[4],  wp[2], c0);
    c1 = pk_fma_bh(h[5],  wp[2], c1);
    c2 = pk_fma_bl(h[6],  wp[3], c2);
    c3 = pk_fma_bh(h[7],  wp[3], c3);
    c0 = pk_fma_bl(h[8],  wp[4], c0);
    c1 = pk_fma_bh(h[9],  wp[4], c1);
    c2 = pk_fma_bl(h[10], wp[5], c2);
    c3 = pk_fma_bh(h[11], wp[5], c3);
    c0 = pk_fma_bl(h[12], wp[6], c0);
    c1 = pk_fma_bh(h[13], wp[6], c1);
    c2 = pk_fma_bl(h[14], wp[7], c2);
    c3 = pk_fma_bh(h[15], wp[7], c3);
    c0 = pk_fma_bl(h[16], wp[8], c0);
    c1 = pk_fma_bh(h[17], wp[8], c1);
    c2 = pk_fma_bl(h[18], wp[9], c2);
    c3 = pk_fma_bh(h[19], wp[9], c3);
    v2f s02 = pk_add(c0, c2);
    v2f s13 = pk_add(c1, c3);
    return pk_add(s02, s13);
}

// Param layout per batch (921 floats):
// [0,40) W1(20x2)  [40,60) b1 | [60,460) W2(20x20) [460,480) b2
// [480,880) W3(20x20) [880,900) b3 | [900,920) W4(1x20) [920] b4
// Scalar weights in LDS (R10 layout); all W rows are 16B-aligned.
__global__ __launch_bounds__(BLOCK) void siren20_pk2_kernel(
    const float* __restrict__ coords,
    const float* __restrict__ wflat,
    float* __restrict__ out)
{
#pragma clang fp contract(off)
    __shared__ __align__(16) float w[928];
    const int b   = blockIdx.y;
    const int tid = threadIdx.x;
    const float* __restrict__ wg = wflat + (size_t)b * 921;

    #pragma unroll
    for (int k = 0; k < 4; ++k) {
        int i = tid + k * BLOCK;
        if (i < 921) w[i] = wg[i];
    }
    __syncthreads();

    const int p0 = blockIdx.x * CHUNK + tid;   // two coalesced points
    const int p1 = p0 + BLOCK;
    const float2* cbase = (const float2*)(coords + (size_t)b * NP * 2);
    const float2 ca = cbase[p0];
    const float2 cc = cbase[p1];
    v2f cx; cx.x = ca.x; cx.y = cc.x;
    v2f cy; cy.x = ca.y; cy.y = cc.y;

    v2f h[20], g[20];

    // Layer 1: n=2 scalar dot (mul, add; no fma), +b, *20, CR sin per lane.
    #pragma unroll
    for (int j = 0; j < 20; ++j) {
        v2f s = cx * w[2 * j];
        s = s + cy * w[2 * j + 1];
        v2f u = s + w[40 + j];
        v2f t = u * 20.0f;
        h[j].x = sin_cr(t.x);
        h[j].y = sin_cr(t.y);
    }

    // Layer 2: W at 60, b at 460 — exact numpy dot (packed), hw sin
    #pragma unroll
    for (int j = 0; j < 20; ++j) {
        const v2f* wp = (const v2f*)&w[60 + 20 * j];
        v2f a = dot20_pk_np(wp, h);
        v2f u = a + w[460 + j];
        v2f t = u * 20.0f;
        g[j] = sin2_hw(t);
    }

    // Layer 3: W at 480, b at 880 — fma dot (packed), hw sin
    #pragma unroll
    for (int j = 0; j < 20; ++j) {
        const v2f* wp = (const v2f*)&w[480 + 20 * j];
        v2f a = dot20_pk_fma(wp, g);
        v2f u = a + w[880 + j];
        v2f t = u * 20.0f;
        h[j] = sin2_hw(t);
    }

    // Layer 4: W at 900, b at 920, clip — fma dot (packed)
    {
        const v2f* wp = (const v2f*)&w[900];
        v2f a = dot20_pk_fma(wp, h);
        v2f u = a + w[920];
        float r0 = fminf(fmaxf(u.x, 0.0f), 1.0f);
        float r1 = fminf(fmaxf(u.y, 0.0f), 1.0f);
        float* ob = out + (size_t)b * NP;
        ob[p0] = r0;
        ob[p1] = r1;
    }
}

extern "C" void kernel_launch(void* const* d_in, const int* in_sizes, int n_in,
                              void* d_out, int out_size, void* d_ws, size_t ws_size,
                              hipStream_t stream) {
    const float* coords = (const float*)d_in[0];
    const float* wflat  = (const float*)d_in[1];
    float* out = (float*)d_out;
    dim3 grid(NCHUNK, NB);
    siren20_pk2_kernel<<<grid, dim3(BLOCK), 0, stream>>>(coords, wflat, out);
}

// Round 12
// 80.667 us; speedup vs baseline: 1.6748x; 1.1464x over previous
//
#include <hip/hip_runtime.h>
#include <math.h>

#define NB    512
#define NP    4096
#define BLOCK 256
#define KPT   2
#define CHUNK (BLOCK * KPT)     // 512 points per block
#define NCHUNK (NP / CHUNK)     // 8 chunks per batch element

typedef float v2f __attribute__((ext_vector_type(2)));

// ---- VOP3P packed f32 with op_sel broadcast of one 32-bit half ----
// wpair = two CONSECUTIVE scalar weights {w[2k], w[2k+1]} read from LDS.
// _bl: both result halves use wpair.lo ; _bh: both use wpair.hi.
// Per-lane semantics = plain IEEE f32 mul/fma -> bit-exact per point.
__device__ __forceinline__ v2f pk_mul_bl(v2f a, v2f w) {
    v2f d;
    asm("v_pk_mul_f32 %0, %1, %2 op_sel:[0,0] op_sel_hi:[1,0]"
        : "=v"(d) : "v"(a), "v"(w));
    return d;
}
__device__ __forceinline__ v2f pk_mul_bh(v2f a, v2f w) {
    v2f d;
    asm("v_pk_mul_f32 %0, %1, %2 op_sel:[0,1] op_sel_hi:[1,1]"
        : "=v"(d) : "v"(a), "v"(w));
    return d;
}
__device__ __forceinline__ v2f pk_fma_bl(v2f a, v2f w, v2f c) {
    v2f d;
    asm("v_pk_fma_f32 %0, %1, %2, %3 op_sel:[0,0,0] op_sel_hi:[1,0,1]"
        : "=v"(d) : "v"(a), "v"(w), "v"(c));
    return d;
}
__device__ __forceinline__ v2f pk_fma_bh(v2f a, v2f w, v2f c) {
    v2f d;
    asm("v_pk_fma_f32 %0, %1, %2, %3 op_sel:[0,1,0] op_sel_hi:[1,1,1]"
        : "=v"(d) : "v"(a), "v"(w), "v"(c));
    return d;
}
__device__ __forceinline__ v2f pk_add(v2f a, v2f b) {
    v2f d;
    asm("v_pk_add_f32 %0, %1, %2 op_sel:[0,0] op_sel_hi:[1,1]"
        : "=v"(d) : "v"(a), "v"(b));
    return d;
}

// fp32 sin for layer 1, near-correctly-rounded (abs err ~9e-10):
// n computed in f32 (a +-1 flip of n shifts x by 2pi -> harmless for the odd
// poly, still accurate at |x|<=pi+3e-5); one f64 fma reduction; deg-19
// Taylor via Estrin (depth ~6 vs Horner's 10).
__device__ __forceinline__ float sin_cr(float tf) {
#pragma clang fp contract(off)
    float yf = tf * 0.15915494309189535f;   // t/(2pi) in f32 (only feeds n)
    float nf = rintf(yf);
    double n  = (double)nf;
    double t  = (double)tf;
    double x  = fma(n, -6.283185307179586, t);   // [-pi-3e-5, pi+3e-5]
    double x2 = x * x;
    double x4 = x2 * x2;
    double x8 = x4 * x4;
    const double c3  = -1.0 / 6.0;
    const double c5  =  1.0 / 120.0;
    const double c7  = -1.0 / 5040.0;
    const double c9  =  1.0 / 362880.0;
    const double c11 = -1.0 / 39916800.0;
    const double c13 =  1.0 / 6227020800.0;
    const double c15 = -1.0 / 1307674368000.0;
    const double c17 =  1.0 / 355687428096000.0;
    const double c19 = -1.0 / 121645100408832000.0;
    double A  = fma(x2, c5,  c3);
    double B  = fma(x2, c9,  c7);
    double C  = fma(x2, c13, c11);
    double D  = fma(x2, c17, c15);
    double AB = fma(x4, B, A);
    double CD = fma(x4, D, C);
    double CDE = fma(x8, c19, CD);
    double P  = fma(x8, CDE, AB);
    double x3 = x2 * x;
    return (float)fma(P, x3, x);
}

// L2/L3 sin of 20*u: fold the x20 and the 1/(2pi) into one multiply:
// y = u * (10/pi) revolutions; s = y - rint(y) in [-0.5,0.5] (exact sub);
// hardware v_sin_f32. Total arg deviation vs numpy's sin(fl(20u)) ~2.6e-5
// rad; output impact <~2e-3 (gain(L2->out) <~60, calibrated R8/R10).
__device__ __forceinline__ v2f sin2_rev(v2f u) {
#pragma clang fp contract(off)
    v2f y = u * 3.1830988618379067f;     // 10/pi
    v2f n;
    n.x = rintf(y.x);
    n.y = rintf(y.y);
    v2f s = y - n;                        // exact (Sterbenz)
    v2f o;
    o.x = __builtin_amdgcn_sinf(s.x);
    o.y = __builtin_amdgcn_sinf(s.y);
    return o;
}

// n=20 dot, numpy column structure (c_l over stride-4, tree (c0+c2)+(c1+c3)),
// fma-contracted, packed via op_sel. Proven at L3/L4 since R10 (absmax
// bit-identical); now also used at L2.
__device__ __forceinline__ v2f dot20_pk_fma(const v2f* __restrict__ wp,
                                            const v2f* __restrict__ h) {
    v2f c0 = pk_mul_bl(h[0],  wp[0]);
    v2f c1 = pk_mul_bh(h[1],  wp[0]);
    v2f c2 = pk_mul_bl(h[2],  wp[1]);
    v2f c3 = pk_mul_bh(h[3],  wp[1]);
    c0 = pk_fma_bl(h[4],  wp[2], c0);
    c1 = pk_fma_bh(h[5],  wp[2], c1);
    c2 = pk_fma_bl(h[6],  wp[3], c2);
    c3 = pk_fma_bh(h[7],  wp[3], c3);
    c0 = pk_fma_bl(h[8],  wp[4], c0);
    c1 = pk_fma_bh(h[9],  wp[4], c1);
    c2 = pk_fma_bl(h[10], wp[5], c2);
    c3 = pk_fma_bh(h[11], wp[5], c3);
    c0 = pk_fma_bl(h[12], wp[6], c0);
    c1 = pk_fma_bh(h[13], wp[6], c1);
    c2 = pk_fma_bl(h[14], wp[7], c2);
    c3 = pk_fma_bh(h[15], wp[7], c3);
    c0 = pk_fma_bl(h[16], wp[8], c0);
    c1 = pk_fma_bh(h[17], wp[8], c1);
    c2 = pk_fma_bl(h[18], wp[9], c2);
    c3 = pk_fma_bh(h[19], wp[9], c3);
    v2f s02 = pk_add(c0, c2);
    v2f s13 = pk_add(c1, c3);
    return pk_add(s02, s13);
}

// Param layout per batch (921 floats):
// [0,40) W1(20x2)  [40,60) b1 | [60,460) W2(20x20) [460,480) b2
// [480,880) W3(20x20) [880,900) b3 | [900,920) W4(1x20) [920] b4
__global__ __launch_bounds__(BLOCK) void siren20_np7_kernel(
    const float* __restrict__ coords,
    const float* __restrict__ wflat,
    float* __restrict__ out)
{
#pragma clang fp contract(off)
    __shared__ __align__(16) float w[928];
    const int b   = blockIdx.y;
    const int tid = threadIdx.x;
    const float* __restrict__ wg = wflat + (size_t)b * 921;

    #pragma unroll
    for (int k = 0; k < 4; ++k) {
        int i = tid + k * BLOCK;
        if (i < 921) w[i] = wg[i];
    }
    __syncthreads();

    const int p0 = blockIdx.x * CHUNK + tid;   // two coalesced points
    const int p1 = p0 + BLOCK;
    const float2* cbase = (const float2*)(coords + (size_t)b * NP * 2);
    const float2 ca = cbase[p0];
    const float2 cc = cbase[p1];
    v2f cx; cx.x = ca.x; cx.y = cc.x;
    v2f cy; cy.x = ca.y; cy.y = cc.y;

    v2f h[20], g[20];

    // Layer 1: n=2 scalar dot (mul, add; no fma), +b, *20 (exact numpy
    // order), near-CR sin per lane.
    #pragma unroll
    for (int j = 0; j < 20; ++j) {
        v2f s = cx * w[2 * j];
        s = s + cy * w[2 * j + 1];
        v2f u = s + w[40 + j];
        v2f t = u * 20.0f;
        h[j].x = sin_cr(t.x);
        h[j].y = sin_cr(t.y);
    }

    // Layer 2: W at 60, b at 460 — pk-fma dot, folded hw sin
    #pragma unroll
    for (int j = 0; j < 20; ++j) {
        const v2f* wp = (const v2f*)&w[60 + 20 * j];
        v2f a = dot20_pk_fma(wp, h);
        v2f u = a + w[460 + j];
        g[j] = sin2_rev(u);
    }

    // Layer 3: W at 480, b at 880 — pk-fma dot, folded hw sin
    #pragma unroll
    for (int j = 0; j < 20; ++j) {
        const v2f* wp = (const v2f*)&w[480 + 20 * j];
        v2f a = dot20_pk_fma(wp, g);
        v2f u = a + w[880 + j];
        h[j] = sin2_rev(u);
    }

    // Layer 4: W at 900, b at 920, clip — pk-fma dot
    {
        const v2f* wp = (const v2f*)&w[900];
        v2f a = dot20_pk_fma(wp, h);
        v2f u = a + w[920];
        float r0 = fminf(fmaxf(u.x, 0.0f), 1.0f);
        float r1 = fminf(fmaxf(u.y, 0.0f), 1.0f);
        float* ob = out + (size_t)b * NP;
        ob[p0] = r0;
        ob[p1] = r1;
    }
}

extern "C" void kernel_launch(void* const* d_in, const int* in_sizes, int n_in,
                              void* d_out, int out_size, void* d_ws, size_t ws_size,
                              hipStream_t stream) {
    const float* coords = (const float*)d_in[0];
    const float* wflat  = (const float*)d_in[1];
    float* out = (float*)d_out;
    dim3 grid(NCHUNK, NB);
    siren20_np7_kernel<<<grid, dim3(BLOCK), 0, stream>>>(coords, wflat, out);
}

// Round 14
// 77.758 us; speedup vs baseline: 1.7374x; 1.0374x over previous
//
#include <hip/hip_runtime.h>
#include <math.h>

#define NB    512
#define NP    4096
#define BLOCK 256
#define KPT   4
#define CHUNK (BLOCK * KPT)     // 1024 points per block
#define NCHUNK (NP / CHUNK)     // 4 chunks per batch element

typedef float v2f __attribute__((ext_vector_type(2)));

// fp32 sin for layer 1, near-correctly-rounded (abs err ~9e-10).
// Identical to R12 (n in f32; one f64 fma reduction; deg-19 Estrin).
__device__ __forceinline__ float sin_cr(float tf) {
#pragma clang fp contract(off)
    float yf = tf * 0.15915494309189535f;
    float nf = rintf(yf);
    double n  = (double)nf;
    double t  = (double)tf;
    double x  = fma(n, -6.283185307179586, t);   // [-pi-3e-5, pi+3e-5]
    double x2 = x * x;
    double x4 = x2 * x2;
    double x8 = x4 * x4;
    const double c3  = -1.0 / 6.0;
    const double c5  =  1.0 / 120.0;
    const double c7  = -1.0 / 5040.0;
    const double c9  =  1.0 / 362880.0;
    const double c11 = -1.0 / 39916800.0;
    const double c13 =  1.0 / 6227020800.0;
    const double c15 = -1.0 / 1307674368000.0;
    const double c17 =  1.0 / 355687428096000.0;
    const double c19 = -1.0 / 121645100408832000.0;
    double A  = fma(x2, c5,  c3);
    double B  = fma(x2, c9,  c7);
    double C  = fma(x2, c13, c11);
    double D  = fma(x2, c17, c15);
    double AB = fma(x4, B, A);
    double CD = fma(x4, D, C);
    double CDE = fma(x8, c19, CD);
    double P  = fma(x8, CDE, AB);
    double x3 = x2 * x;
    return (float)fma(P, x3, x);
}

// L2/L3 sin of 20*u (identical to R12): y = u*(10/pi) revolutions,
// s = y - rint(y) in [-0.5,0.5] (exact), hardware v_sin_f32.
__device__ __forceinline__ v2f sin2_rev(v2f u) {
#pragma clang fp contract(off)
    v2f y = u * 3.1830988618379067f;     // 10/pi
    v2f n;
    n.x = rintf(y.x);
    n.y = rintf(y.y);
    v2f s = y - n;                        // exact
    v2f o;
    o.x = __builtin_amdgcn_sinf(s.x);
    o.y = __builtin_amdgcn_sinf(s.y);
    return o;
}

// n=20 dot, numpy column structure (stride-4 columns, tree (c0+c2)+(c1+c3)),
// fma-contracted (per-lane fma semantics — proven bit-safe at L2/L3/L4 in
// R10/R12). Plain v2f: R11 showed this is performance-equal to explicit
// VOP3P asm, and it leaves the compiler free to schedule/CSE under pressure.
__device__ __forceinline__ v2f dot20_fma(const float* __restrict__ wr,
                                         const v2f* __restrict__ h) {
#pragma clang fp contract(fast)
    v2f c0 = h[0] * wr[0];
    v2f c1 = h[1] * wr[1];
    v2f c2 = h[2] * wr[2];
    v2f c3 = h[3] * wr[3];
    c0 = c0 + h[4]  * wr[4];   c1 = c1 + h[5]  * wr[5];
    c2 = c2 + h[6]  * wr[6];   c3 = c3 + h[7]  * wr[7];
    c0 = c0 + h[8]  * wr[8];   c1 = c1 + h[9]  * wr[9];
    c2 = c2 + h[10] * wr[10];  c3 = c3 + h[11] * wr[11];
    c0 = c0 + h[12] * wr[12];  c1 = c1 + h[13] * wr[13];
    c2 = c2 + h[14] * wr[14];  c3 = c3 + h[15] * wr[15];
    c0 = c0 + h[16] * wr[16];  c1 = c1 + h[17] * wr[17];
    c2 = c2 + h[18] * wr[18];  c3 = c3 + h[19] * wr[19];
    v2f s02 = c0 + c2;
    v2f s13 = c1 + c3;
    return s02 + s13;
}

// Param layout per batch (921 floats):
// [0,40) W1(20x2)  [40,60) b1 | [60,460) W2(20x20) [460,480) b2
// [480,880) W3(20x20) [880,900) b3 | [900,920) W4(1x20) [920] b4
__global__ __launch_bounds__(BLOCK) void siren20_np9_kernel(
    const float* __restrict__ coords,
    const float* __restrict__ wflat,
    float* __restrict__ out)
{
#pragma clang fp contract(off)
    __shared__ __align__(16) float w[928];
    const int b   = blockIdx.y;
    const int tid = threadIdx.x;
    const float* __restrict__ wg = wflat + (size_t)b * 921;

    #pragma unroll
    for (int k = 0; k < 4; ++k) {
        int i = tid + k * BLOCK;
        if (i < 921) w[i] = wg[i];
    }
    __syncthreads();

    const int p0 = blockIdx.x * CHUNK + tid;   // four coalesced points
    const float2* cbase = (const float2*)(coords + (size_t)b * NP * 2);
    const float2 cA0 = cbase[p0];
    const float2 cA1 = cbase[p0 + BLOCK];
    const float2 cB0 = cbase[p0 + 2 * BLOCK];
    const float2 cB1 = cbase[p0 + 3 * BLOCK];
    v2f cxA; cxA.x = cA0.x; cxA.y = cA1.x;
    v2f cyA; cyA.x = cA0.y; cyA.y = cA1.y;
    v2f cxB; cxB.x = cB0.x; cxB.y = cB1.x;
    v2f cyB; cyB.x = cB0.y; cyB.y = cB1.y;

    v2f hA[20], gA[20], hB[20], gB[20];

    // Layer 1: n=2 scalar dot (mul, add; no fma), +b, *20, near-CR sin.
    #pragma unroll
    for (int j = 0; j < 20; ++j) {
        const float w0 = w[2 * j], w1 = w[2 * j + 1], bb = w[40 + j];
        v2f sA = cxA * w0;
        sA = sA + cyA * w1;
        v2f uA = sA + bb;
        v2f tA = uA * 20.0f;
        hA[j].x = sin_cr(tA.x);
        hA[j].y = sin_cr(tA.y);
        v2f sB = cxB * w0;
        sB = sB + cyB * w1;
        v2f uB = sB + bb;
        v2f tB = uB * 20.0f;
        hB[j].x = sin_cr(tB.x);
        hB[j].y = sin_cr(tB.y);
    }

    // Layer 2: W at 60, b at 460 — two fma dots sharing weight loads (CSE)
    #pragma unroll
    for (int j = 0; j < 20; ++j) {
        const float* wr = &w[60 + 20 * j];
        v2f aA = dot20_fma(wr, hA);
        v2f aB = dot20_fma(wr, hB);
        const float bb = w[460 + j];
        gA[j] = sin2_rev(aA + bb);
        gB[j] = sin2_rev(aB + bb);
    }

    // Layer 3: W at 480, b at 880
    #pragma unroll
    for (int j = 0; j < 20; ++j) {
        const float* wr = &w[480 + 20 * j];
        v2f aA = dot20_fma(wr, gA);
        v2f aB = dot20_fma(wr, gB);
        const float bb = w[880 + j];
        hA[j] = sin2_rev(aA + bb);
        hB[j] = sin2_rev(aB + bb);
    }

    // Layer 4: W at 900, b at 920, clip
    {
        const float* wr = &w[900];
        v2f aA = dot20_fma(wr, hA);
        v2f aB = dot20_fma(wr, hB);
        const float bb = w[920];
        v2f uA = aA + bb;
        v2f uB = aB + bb;
        float* ob = out + (size_t)b * NP;
        ob[p0]             = fminf(fmaxf(uA.x, 0.0f), 1.0f);
        ob[p0 + BLOCK]     = fminf(fmaxf(uA.y, 0.0f), 1.0f);
        ob[p0 + 2 * BLOCK] = fminf(fmaxf(uB.x, 0.0f), 1.0f);
        ob[p0 + 3 * BLOCK] = fminf(fmaxf(uB.y, 0.0f), 1.0f);
    }
}

extern "C" void kernel_launch(void* const* d_in, const int* in_sizes, int n_in,
                              void* d_out, int out_size, void* d_ws, size_t ws_size,
                              hipStream_t stream) {
    const float* coords = (const float*)d_in[0];
    const float* wflat  = (const float*)d_in[1];
    float* out = (float*)d_out;
    dim3 grid(NCHUNK, NB);
    siren20_np9_kernel<<<grid, dim3(BLOCK), 0, stream>>>(coords, wflat, out);
}